// Round 11
// baseline (368.646 us; speedup 1.0000x reference)
//
#include <hip/hip_runtime.h>
#include <stdint.h>

typedef unsigned short u16;
typedef unsigned int u32;

using bf16x8 = __attribute__((ext_vector_type(8))) short;
using f32x4  = __attribute__((ext_vector_type(4))) float;

#define DEVINL __device__ __forceinline__

DEVINL float b2f(u16 u) { return __builtin_bit_cast(float, (u32)u << 16); }
DEVINL u16 f2b(float f) {
  u32 u = __builtin_bit_cast(u32, f);
  u += 0x7FFFu + ((u >> 16) & 1u);   // round-to-nearest-even
  return (u16)(u >> 16);
}

DEVINL void gll16(const u16* src, u16* dst) {
  __builtin_amdgcn_global_load_lds(
      (const __attribute__((address_space(1))) void*)(uintptr_t)src,
      (__attribute__((address_space(3))) void*)(uintptr_t)dst, 16, 0, 0);
}

#define MFMA __builtin_amdgcn_mfma_f32_16x16x32_bf16
#define NROLE 6
#define PROWS 33152          // 518 * 64 padded row space
#define PBLK  518

// ---------------------------------------------------------------- role_count
__global__ __launch_bounds__(256) void role_count(
    const int* __restrict__ rid, int* __restrict__ blkCnt)
{
  __shared__ int h[NROLE];
  if (threadIdx.x < NROLE) h[threadIdx.x] = 0;
  __syncthreads();
  atomicAdd(&h[rid[blockIdx.x * 256 + threadIdx.x]], 1);
  __syncthreads();
  if (threadIdx.x < NROLE) blkCnt[blockIdx.x * NROLE + threadIdx.x] = h[threadIdx.x];
}

// ---------------------------------------------------------------- fill body (padded bucket)
DEVINL void fill_body(
    const int* __restrict__ rid, const int* __restrict__ blkCnt,
    int* __restrict__ bucket, int* __restrict__ pbaseOut, int* __restrict__ cntArr,
    int bx)
{
  __shared__ int c[128 * NROLE];
  __shared__ int preArr[NROLE], scnt[NROLE], pb[NROLE + 1], h[NROLE];
  const int tid = threadIdx.x;
  for (int i = tid; i < 128 * NROLE; i += 256) c[i] = blkCnt[i];
  if (tid < NROLE) h[tid] = 0;
  __syncthreads();
  if (tid < NROLE) {
    int k = tid, run = 0, pre = 0;
    for (int b = 0; b < 128; ++b) { if (b == bx) pre = run; run += c[b * NROLE + k]; }
    scnt[k] = run; preArr[k] = pre;
  }
  __syncthreads();
  if (tid == 0) {
    pb[0] = 0;
    for (int k = 0; k < NROLE; ++k) pb[k + 1] = pb[k] + ((scnt[k] + 63) & ~63);
  }
  __syncthreads();
  if (bx == 0) {
    if (tid <= NROLE) pbaseOut[tid] = pb[tid];
    if (tid < NROLE) cntArr[tid] = scnt[tid];
    for (int k = 0; k < NROLE; ++k)
      for (int p = pb[k] + scnt[k] + tid; p < pb[k + 1]; p += 256) bucket[p] = 0;
    for (int p = pb[NROLE] + tid; p < PROWS; p += 256) bucket[p] = 0;
  }
  int i = bx * 256 + tid;
  int k = rid[i];
  int pos = atomicAdd(&h[k], 1);
  bucket[pb[k] + preArr[k] + pos] = i;
}

// ---------------------------------------------------------------- prep: transposes + rnn copy + fill
DEVINL void tp_tile(const float* __restrict__ s, u16* __restrict__ d,
                    int R, int C, int bx, int by, int z)
{
  __shared__ u16 tile[32][33];
  const size_t mstride = (size_t)R * C;
  s += (size_t)z * mstride;
  d += (size_t)z * mstride;
  int r0 = bx * 32, c0 = by * 32;
  int tx = threadIdx.x & 31, ty = threadIdx.x >> 5;
#pragma unroll
  for (int i = 0; i < 32; i += 8)
    tile[ty + i][tx] = f2b(s[(size_t)(r0 + ty + i) * C + (c0 + tx)]);
  __syncthreads();
#pragma unroll
  for (int i = 0; i < 32; i += 8)
    d[(size_t)(c0 + ty + i) * R + (r0 + tx)] = tile[tx][ty + i];
}

__global__ __launch_bounds__(256) void prep(
    const float* W0, const float* W1, const float* Wr0, const float* Wr1, const float* Wh0,
    u16* W0t, u16* W1t, u16* Wr0t, u16* Wr1t, u16* Wh0t,
    const float* __restrict__ rnn, float* __restrict__ outRnn,
    const int* __restrict__ rid, const int* __restrict__ blkCnt,
    int* __restrict__ bucket, int* __restrict__ pbase, int* __restrict__ cntArr)
{
  int b = blockIdx.x;
  const int tid = threadIdx.x;
  if (b < 1152) {
    if (b < 128)      {            tp_tile(W0, W0t, 256, 512, b % 8,  b / 8, 0); }
    else if (b < 384) { b -= 128;  tp_tile(W1, W1t, 512, 512, b % 16, b / 16, 0); }
    else if (b < 576) { b -= 384;  int t = b / 8;  tp_tile(Wr0, Wr0t, 256, 128, b % 8,  t % 4,  t / 4); }
    else if (b < 960) { b -= 576;  int t = b / 4;  tp_tile(Wr1, Wr1t, 128, 512, b % 4,  t % 16, t / 16); }
    else              { b -= 960;  int t = b / 16; tp_tile(Wh0, Wh0t, 512, 64,  b % 16, t % 2,  t / 2); }
  } else if (b < 1280) {
    b -= 1152;
    const float4* src = (const float4*)rnn;
    float4* dst = (float4*)outRnn;
    int base = (b * 256 + tid) * 4;
#pragma unroll
    for (int i = 0; i < 4; ++i) dst[base + i] = src[base + i];
  } else {
    fill_body(rid, blkCnt, bucket, pbase, cntArr, b - 1280);
  }
}

// ---------------------------------------------------------------- stage1:
// per 64 bucket-rows: LN(obs[g]) -> A-tile in LDS (zero-barrier K-loops after);
// route0: r1 = relu(A @ Wr0k^T + br0) -> global (row-major)
// layer0: bufA = LN(relu(A @ W0^T + b0))
__global__ __launch_bounds__(256, 2) void stage1_k(
    const float* __restrict__ obs, const float* __restrict__ fn_s,
    const float* __restrict__ fn_b,
    const u16* __restrict__ W0t, const float* __restrict__ b0,
    const float* __restrict__ ln0s, const float* __restrict__ ln0b,
    const u16* __restrict__ Wr0t, const float* __restrict__ br0,
    const int* __restrict__ bucket, const int* __restrict__ pbase,
    u16* __restrict__ bufA, u16* __restrict__ r1out)
{
  __shared__ __align__(16) u16 As[64 * 256];       // 32 KB
  __shared__ float redS[64][4], redSS[64][4];
  __shared__ float prm[1664];   // b0 512 | ln0s 512 | ln0b 512 | br0 128
  const int tid = threadIdx.x;
  const int rowBase = blockIdx.x * 64;
  if (rowBase >= pbase[NROLE]) return;
  int role = 0;
  while (rowBase >= pbase[role + 1]) ++role;
  const int lane = tid & 63, wave = tid >> 6;
  const int quad = lane >> 4, lm = lane & 15, l7 = lm & 7;

#pragma unroll
  for (int i = tid; i < 512; i += 256) {
    prm[i] = b0[i]; prm[512 + i] = ln0s[i]; prm[1024 + i] = ln0b[i];
  }
  if (tid < 128) prm[1536 + tid] = br0[role * 128 + tid];

  // ---- LN obs rows -> LDS A-tile (source-order swizzled)
  for (int it = 0; it < 16; ++it) {
    int row = wave * 16 + it;
    int g = bucket[rowBase + row];
    float x[4] __attribute__((aligned(16)));
    *(float4*)x = *(const float4*)(obs + (size_t)g * 256 + lane * 4);
    float s = 0.f, s2 = 0.f;
#pragma unroll
    for (int q = 0; q < 4; ++q) { s += x[q]; s2 += x[q] * x[q]; }
#pragma unroll
    for (int o = 32; o > 0; o >>= 1) { s += __shfl_xor(s, o, 64); s2 += __shfl_xor(s2, o, 64); }
    float m = s * (1.f / 256.f);
    float v = s2 * (1.f / 256.f) - m * m;
    float inv = rsqrtf(v + 1e-5f);
    u16 yu[4] __attribute__((aligned(8)));
#pragma unroll
    for (int q = 0; q < 4; ++q)
      yu[q] = f2b((x[q] - m) * inv * fn_s[lane * 4 + q] + fn_b[lane * 4 + q]);
    // LDS slot c of row r holds global chunk c ^ (r&7)
    *(uint2*)&As[row * 256 + (((lane >> 1) ^ (row & 7)) * 8) + (lane & 1) * 4] = *(uint2*)yu;
  }
  __syncthreads();

  // ---- route0: N=128 (wave covers 32 cols), K=256, zero-barrier
  {
    const int wn0 = wave * 32;
    const u16* B0 = Wr0t + (size_t)role * 128 * 256;
    f32x4 acc[4][2] = {};
#pragma unroll
    for (int kc = 0; kc < 8; ++kc) {
      bf16x8 af[4], bw[2];
#pragma unroll
      for (int j = 0; j < 2; ++j)
        bw[j] = *(const bf16x8*)(B0 + (u32)(wn0 + j * 16 + lm) * 256u + (u32)(kc * 32 + quad * 8));
#pragma unroll
      for (int i2 = 0; i2 < 4; ++i2)
        af[i2] = *(const bf16x8*)&As[(i2 * 16 + lm) * 256 + ((((quad + kc * 4) ^ l7) & 31) * 8)];
#pragma unroll
      for (int i2 = 0; i2 < 4; ++i2)
#pragma unroll
        for (int j = 0; j < 2; ++j)
          acc[i2][j] = MFMA(af[i2], bw[j], acc[i2][j], 0, 0, 0);
    }
#pragma unroll
    for (int i2 = 0; i2 < 4; ++i2)
#pragma unroll
      for (int r2 = 0; r2 < 4; ++r2) {
        size_t row = (size_t)(rowBase + i2 * 16 + quad * 4 + r2);
#pragma unroll
        for (int j = 0; j < 2; ++j) {
          int col = wn0 + j * 16 + lm;
          r1out[row * 128 + col] = f2b(fmaxf(acc[i2][j][r2] + prm[1536 + col], 0.f));
        }
      }
  }

  // ---- layer0 GEMM+LN: N=512 (wave covers 128), K=256, zero-barrier
  {
    const int wn = wave * 128;
    f32x4 acc[4][8] = {};
#pragma unroll
    for (int kc = 0; kc < 8; ++kc) {
      bf16x8 af[4], bw[8];
#pragma unroll
      for (int j = 0; j < 8; ++j)
        bw[j] = *(const bf16x8*)(W0t + (u32)(wn + j * 16 + lm) * 256u + (u32)(kc * 32 + quad * 8));
#pragma unroll
      for (int i2 = 0; i2 < 4; ++i2)
        af[i2] = *(const bf16x8*)&As[(i2 * 16 + lm) * 256 + ((((quad + kc * 4) ^ l7) & 31) * 8)];
#pragma unroll
      for (int i2 = 0; i2 < 4; ++i2)
#pragma unroll
        for (int j = 0; j < 8; ++j)
          acc[i2][j] = MFMA(af[i2], bw[j], acc[i2][j], 0, 0, 0);
    }
    // bias+relu+LN
#pragma unroll
    for (int i2 = 0; i2 < 4; ++i2)
#pragma unroll
      for (int r2 = 0; r2 < 4; ++r2) {
        float s = 0.f, ss = 0.f;
#pragma unroll
        for (int j = 0; j < 8; ++j) {
          float v = fmaxf(acc[i2][j][r2] + prm[wn + j * 16 + lm], 0.f);
          acc[i2][j][r2] = v; s += v; ss += v * v;
        }
#pragma unroll
        for (int o = 1; o < 16; o <<= 1) { s += __shfl_xor(s, o, 64); ss += __shfl_xor(ss, o, 64); }
        if (lm == 0) {
          int rowL = i2 * 16 + quad * 4 + r2;
          redS[rowL][wave] = s; redSS[rowL][wave] = ss;
        }
      }
    __syncthreads();
#pragma unroll
    for (int i2 = 0; i2 < 4; ++i2)
#pragma unroll
      for (int r2 = 0; r2 < 4; ++r2) {
        int rowL = i2 * 16 + quad * 4 + r2;
        float ts  = redS[rowL][0] + redS[rowL][1] + redS[rowL][2] + redS[rowL][3];
        float tss = redSS[rowL][0] + redSS[rowL][1] + redSS[rowL][2] + redSS[rowL][3];
        float m = ts * (1.f / 512.f);
        float var = tss * (1.f / 512.f) - m * m;
        float inv = rsqrtf(var + 1e-5f);
        size_t base = (size_t)(rowBase + rowL) * 512;
#pragma unroll
        for (int j = 0; j < 8; ++j) {
          int col = wn + j * 16 + lm;
          bufA[base + col] = f2b((acc[i2][j][r2] - m) * inv * prm[512 + col] + prm[1024 + col]);
        }
      }
  }
}

// ---------------------------------------------------------------- stage2:
// per 64 rows: stage bufA tile -> e=LN(relu(A@W1+b1)) -> ea = e + relu(r1@Wr1+br1)
//   -> h0 = relu(ea@Wh0+bh0) -> 64->32->32 tail + mask -> logits. One staging barrier.
__global__ __launch_bounds__(256, 2) void stage2_k(
    const u16* __restrict__ bufA, const u16* __restrict__ W1t,
    const float* __restrict__ b1, const float* __restrict__ ln1s,
    const float* __restrict__ ln1b,
    const u16* __restrict__ r1, const u16* __restrict__ Wr1t,
    const float* __restrict__ br1,
    const u16* __restrict__ Wh0t, const float* __restrict__ bh0,
    const float* __restrict__ Wh1, const float* __restrict__ bh1,
    const float* __restrict__ Wh2, const float* __restrict__ bh2,
    const float* __restrict__ avail, const int* __restrict__ bucket,
    const int* __restrict__ pbase, const int* __restrict__ cntArr,
    float* __restrict__ outLogits)
{
  __shared__ __align__(16) u16 As[64 * 512];       // 64 KB: A-tile, then ea, then h0s/h1s
  __shared__ float redS[64][4], redSS[64][4];
  __shared__ float prm[2112];   // b1 512 | ln1s 512 | ln1b 512 | br1 512 | bh0 64
  const int tid = threadIdx.x;
  const int rowBase = blockIdx.x * 64;
  if (rowBase >= pbase[NROLE]) return;
  int role = 0;
  while (rowBase >= pbase[role + 1]) ++role;
  const int lane = tid & 63, wave = tid >> 6;
  const int quad = lane >> 4, lm = lane & 15, l7 = lm & 7;

  // ---- stage bufA tile (16 rounds, 4 rows each; source chunk-swizzled)
#pragma unroll
  for (int rr = 0; rr < 16; ++rr) {
    int row = rr * 4 + wave;
    gll16(bufA + (size_t)(rowBase + row) * 512 + (u32)(((lane ^ (row & 7)) & 63) * 8),
          &As[row * 512 + lane * 8]);
  }
#pragma unroll
  for (int i = tid; i < 512; i += 256) {
    prm[i] = b1[i]; prm[512 + i] = ln1s[i]; prm[1024 + i] = ln1b[i];
    prm[1536 + i] = br1[role * 512 + i];
  }
  if (tid < 64) prm[2048 + tid] = bh0[role * 64 + tid];
  __syncthreads();

  const int wn = wave * 128;

  // ---- GEMM1: e = LN(relu(A @ W1^T + b1)), K=512, zero-barrier
  {
    f32x4 acc[4][8] = {};
#pragma unroll
    for (int kc = 0; kc < 16; ++kc) {
      bf16x8 af[4], bw[8];
#pragma unroll
      for (int j = 0; j < 8; ++j)
        bw[j] = *(const bf16x8*)(W1t + (u32)(wn + j * 16 + lm) * 512u + (u32)(kc * 32 + quad * 8));
#pragma unroll
      for (int i2 = 0; i2 < 4; ++i2)
        af[i2] = *(const bf16x8*)&As[(i2 * 16 + lm) * 512 + ((((quad + kc * 4) ^ l7) & 63) * 8)];
#pragma unroll
      for (int i2 = 0; i2 < 4; ++i2)
#pragma unroll
        for (int j = 0; j < 8; ++j)
          acc[i2][j] = MFMA(af[i2], bw[j], acc[i2][j], 0, 0, 0);
    }
#pragma unroll
    for (int i2 = 0; i2 < 4; ++i2)
#pragma unroll
      for (int r2 = 0; r2 < 4; ++r2) {
        float s = 0.f, ss = 0.f;
#pragma unroll
        for (int j = 0; j < 8; ++j) {
          float v = fmaxf(acc[i2][j][r2] + prm[wn + j * 16 + lm], 0.f);
          acc[i2][j][r2] = v; s += v; ss += v * v;
        }
#pragma unroll
        for (int o = 1; o < 16; o <<= 1) { s += __shfl_xor(s, o, 64); ss += __shfl_xor(ss, o, 64); }
        if (lm == 0) {
          int rowL = i2 * 16 + quad * 4 + r2;
          redS[rowL][wave] = s; redSS[rowL][wave] = ss;
        }
      }
    __syncthreads();   // also guarantees all A-reads done before e overwrites As
#pragma unroll
    for (int i2 = 0; i2 < 4; ++i2)
#pragma unroll
      for (int r2 = 0; r2 < 4; ++r2) {
        int row = i2 * 16 + quad * 4 + r2;
        float ts  = redS[row][0] + redS[row][1] + redS[row][2] + redS[row][3];
        float tss = redSS[row][0] + redSS[row][1] + redSS[row][2] + redSS[row][3];
        float m = ts * (1.f / 512.f);
        float var = tss * (1.f / 512.f) - m * m;
        float inv = rsqrtf(var + 1e-5f);
#pragma unroll
        for (int j = 0; j < 8; ++j) {
          int col = wn + j * 16 + lm;
          float e = (acc[i2][j][r2] - m) * inv * prm[512 + col] + prm[1024 + col];
          As[row * 512 + ((((col >> 3) ^ (row & 7)) ) * 8) + (col & 7)] = f2b(e);
        }
      }
  }
  __syncthreads();

  // ---- GEMM2: ea = e + relu(r1 @ Wr1^T + br1); A-frags direct from global r1 (L2-hot)
  {
    const u16* B1 = Wr1t + (size_t)role * 512 * 128;
    f32x4 acc[4][8] = {};
#pragma unroll
    for (int kc = 0; kc < 4; ++kc) {
      bf16x8 af[4], bw[8];
#pragma unroll
      for (int j = 0; j < 8; ++j)
        bw[j] = *(const bf16x8*)(B1 + (u32)(wn + j * 16 + lm) * 128u + (u32)(kc * 32 + quad * 8));
#pragma unroll
      for (int i2 = 0; i2 < 4; ++i2)
        af[i2] = *(const bf16x8*)(r1 + (size_t)(rowBase + i2 * 16 + lm) * 128 + (u32)(kc * 32 + quad * 8));
#pragma unroll
      for (int i2 = 0; i2 < 4; ++i2)
#pragma unroll
        for (int j = 0; j < 8; ++j)
          acc[i2][j] = MFMA(af[i2], bw[j], acc[i2][j], 0, 0, 0);
    }
#pragma unroll
    for (int i2 = 0; i2 < 4; ++i2)
#pragma unroll
      for (int r2 = 0; r2 < 4; ++r2) {
        int row = i2 * 16 + quad * 4 + r2;
#pragma unroll
        for (int j = 0; j < 8; ++j) {
          int col = wn + j * 16 + lm;
          int addr = row * 512 + (((col >> 3) ^ (row & 7)) * 8) + (col & 7);
          float v = fmaxf(acc[i2][j][r2] + prm[1536 + col], 0.f) + b2f(As[addr]);
          As[addr] = f2b(v);
        }
      }
  }
  __syncthreads();

  // ---- GEMM3: h0 = relu(ea @ Wh0^T + bh0), N=64 (wave covers 16 cols), K=512
  f32x4 acc3[4] = {};
  {
    const int col0 = wave * 16 + lm;
    const u16* B2 = Wh0t + (size_t)role * 64 * 512;
#pragma unroll
    for (int kc = 0; kc < 16; ++kc) {
      bf16x8 af[4];
      bf16x8 bw = *(const bf16x8*)(B2 + (u32)col0 * 512u + (u32)(kc * 32 + quad * 8));
#pragma unroll
      for (int i2 = 0; i2 < 4; ++i2)
        af[i2] = *(const bf16x8*)&As[(i2 * 16 + lm) * 512 + ((((quad + kc * 4) ^ l7) & 63) * 8)];
#pragma unroll
      for (int i2 = 0; i2 < 4; ++i2)
        acc3[i2] = MFMA(af[i2], bw, acc3[i2], 0, 0, 0);
    }
  }
  __syncthreads();   // all ea reads done; As region free for h0s/h1s

  u16* h0s = As;                        // 64 rows x stride 68 u16
  {
    const int col0 = wave * 16 + lm;
    float bv = prm[2048 + col0];
#pragma unroll
    for (int i2 = 0; i2 < 4; ++i2)
#pragma unroll
      for (int r2 = 0; r2 < 4; ++r2) {
        int row = i2 * 16 + quad * 4 + r2;
        h0s[row * 68 + col0] = f2b(fmaxf(acc3[i2][r2] + bv, 0.f));
      }
  }
  __syncthreads();

  // ---- tail: thread t -> row r=t>>2, 8 cols n0=(t&3)*8
  {
    float* h1s = (float*)&As[16384];    // 64 x 36 f32 (byte offset 32768)
    const int r = tid >> 2;
    const int n0 = (tid & 3) * 8;
    const float* W1k = Wh1 + (size_t)role * 64 * 32;
    const float* W2k = Wh2 + (size_t)role * 32 * 32;
    float4 a1a = *(const float4*)(bh1 + role * 32 + n0);
    float4 a1b = *(const float4*)(bh1 + role * 32 + n0 + 4);
#pragma unroll 8
    for (int j = 0; j < 64; ++j) {
      float hj = b2f(h0s[r * 68 + j]);
      float4 wa = *(const float4*)(W1k + j * 32 + n0);
      float4 wb = *(const float4*)(W1k + j * 32 + n0 + 4);
      a1a.x += hj * wa.x; a1a.y += hj * wa.y; a1a.z += hj * wa.z; a1a.w += hj * wa.w;
      a1b.x += hj * wb.x; a1b.y += hj * wb.y; a1b.z += hj * wb.z; a1b.w += hj * wb.w;
    }
    h1s[r * 36 + n0 + 0] = fmaxf(a1a.x, 0.f);
    h1s[r * 36 + n0 + 1] = fmaxf(a1a.y, 0.f);
    h1s[r * 36 + n0 + 2] = fmaxf(a1a.z, 0.f);
    h1s[r * 36 + n0 + 3] = fmaxf(a1a.w, 0.f);
    h1s[r * 36 + n0 + 4] = fmaxf(a1b.x, 0.f);
    h1s[r * 36 + n0 + 5] = fmaxf(a1b.y, 0.f);
    h1s[r * 36 + n0 + 6] = fmaxf(a1b.z, 0.f);
    h1s[r * 36 + n0 + 7] = fmaxf(a1b.w, 0.f);
    __syncthreads();
    float4 a2a = *(const float4*)(bh2 + role * 32 + n0);
    float4 a2b = *(const float4*)(bh2 + role * 32 + n0 + 4);
#pragma unroll 8
    for (int n = 0; n < 32; ++n) {
      float hn = h1s[r * 36 + n];
      float4 wa = *(const float4*)(W2k + n * 32 + n0);
      float4 wb = *(const float4*)(W2k + n * 32 + n0 + 4);
      a2a.x += hn * wa.x; a2a.y += hn * wa.y; a2a.z += hn * wa.z; a2a.w += hn * wa.w;
      a2b.x += hn * wb.x; a2b.y += hn * wb.y; a2b.z += hn * wb.z; a2b.w += hn * wb.w;
    }
    int local = rowBase + r - pbase[role];
    if (local < cntArr[role]) {
      int g = bucket[rowBase + r];
      float4 ava = *(const float4*)(avail + (size_t)g * 32 + n0);
      float4 avb = *(const float4*)(avail + (size_t)g * 32 + n0 + 4);
      float4 oa, ob;
      oa.x = (ava.x > 0.5f) ? a2a.x : -1e10f;
      oa.y = (ava.y > 0.5f) ? a2a.y : -1e10f;
      oa.z = (ava.z > 0.5f) ? a2a.z : -1e10f;
      oa.w = (ava.w > 0.5f) ? a2a.w : -1e10f;
      ob.x = (avb.x > 0.5f) ? a2b.x : -1e10f;
      ob.y = (avb.y > 0.5f) ? a2b.y : -1e10f;
      ob.z = (avb.z > 0.5f) ? a2b.z : -1e10f;
      ob.w = (avb.w > 0.5f) ? a2b.w : -1e10f;
      *(float4*)(outLogits + (size_t)g * 32 + n0) = oa;
      *(float4*)(outLogits + (size_t)g * 32 + n0 + 4) = ob;
    }
  }
}

// ---------------------------------------------------------------- launcher
extern "C" void kernel_launch(void* const* d_in, const int* in_sizes, int n_in,
                              void* d_out, int out_size, void* d_ws, size_t ws_size,
                              hipStream_t stream)
{
  const float* rnn  = (const float*)d_in[0];
  const float* obs  = (const float*)d_in[1];
  const float* avail= (const float*)d_in[3];
  const int*   rid  = (const int*)d_in[4];
  const float* fn_s = (const float*)d_in[5];
  const float* fn_b = (const float*)d_in[6];
  const float* W0   = (const float*)d_in[7];
  const float* b0   = (const float*)d_in[8];
  const float* ln0s = (const float*)d_in[9];
  const float* ln0b = (const float*)d_in[10];
  const float* W1   = (const float*)d_in[11];
  const float* b1   = (const float*)d_in[12];
  const float* ln1s = (const float*)d_in[13];
  const float* ln1b = (const float*)d_in[14];
  const float* Wr0  = (const float*)d_in[15];
  const float* br0  = (const float*)d_in[16];
  const float* Wr1  = (const float*)d_in[17];
  const float* br1  = (const float*)d_in[18];
  const float* Wh0  = (const float*)d_in[19];
  const float* bh0  = (const float*)d_in[20];
  const float* Wh1  = (const float*)d_in[21];
  const float* bh1  = (const float*)d_in[22];
  const float* Wh2  = (const float*)d_in[23];
  const float* bh2  = (const float*)d_in[24];

  char* w = (char*)d_ws;
  auto carve = [&](size_t bytes) { char* p = w; w += (bytes + 255) & ~(size_t)255; return p; };
  u16* bufA   = (u16*)carve((size_t)PROWS * 512 * 2);
  u16* r1buf  = (u16*)carve((size_t)PROWS * 128 * 2);
  u16* W0t    = (u16*)carve((size_t)512 * 256 * 2);
  u16* W1t    = (u16*)carve((size_t)512 * 512 * 2);
  u16* Wr0t   = (u16*)carve((size_t)6 * 128 * 256 * 2);
  u16* Wr1t   = (u16*)carve((size_t)6 * 512 * 128 * 2);
  u16* Wh0t   = (u16*)carve((size_t)6 * 64 * 512 * 2);
  int* bucket = (int*)carve((size_t)PROWS * 4);
  int* blkCnt = (int*)carve((size_t)128 * NROLE * 4);
  int* pbase  = (int*)carve(256);
  int* cntArr = (int*)carve(256);

  float* outLogits = (float*)d_out + (size_t)1024 * 512;

  role_count<<<128, 256, 0, stream>>>(rid, blkCnt);

  // transposes + rnn passthrough + bucket fill
  prep<<<1408, 256, 0, stream>>>(W0, W1, Wr0, Wr1, Wh0, W0t, W1t, Wr0t, Wr1t, Wh0t,
                                 rnn, (float*)d_out, rid, blkCnt, bucket, pbase, cntArr);

  // stage1: obs-LN + layer0 GEMM+LN + route0
  stage1_k<<<PBLK, 256, 0, stream>>>(obs, fn_s, fn_b, W0t, b0, ln0s, ln0b,
                                     Wr0t, br0, bucket, pbase, bufA, r1buf);

  // stage2: layer1 GEMM+LN + route1 + head + mask -> logits
  stage2_k<<<PBLK, 256, 0, stream>>>(bufA, W1t, b1, ln1s, ln1b,
                                     r1buf, Wr1t, br1, Wh0t, bh0,
                                     Wh1, bh1, Wh2, bh2, avail,
                                     bucket, pbase, cntArr, outLogits);
}

// Round 12
// 267.313 us; speedup vs baseline: 1.3791x; 1.3791x over previous
//
#include <hip/hip_runtime.h>
#include <stdint.h>

typedef unsigned short u16;
typedef unsigned int u32;

using bf16x8 = __attribute__((ext_vector_type(8))) short;
using f32x4  = __attribute__((ext_vector_type(4))) float;

#define DEVINL __device__ __forceinline__

DEVINL float b2f(u16 u) { return __builtin_bit_cast(float, (u32)u << 16); }
DEVINL u16 f2b(float f) {
  u32 u = __builtin_bit_cast(u32, f);
  u += 0x7FFFu + ((u >> 16) & 1u);   // round-to-nearest-even
  return (u16)(u >> 16);
}

DEVINL void gll16(const u16* src, u16* dst) {
  __builtin_amdgcn_global_load_lds(
      (const __attribute__((address_space(1))) void*)(uintptr_t)src,
      (__attribute__((address_space(3))) void*)(uintptr_t)dst, 16, 0, 0);
}

#define MFMA __builtin_amdgcn_mfma_f32_16x16x32_bf16
#define NROLE 6

// ---------------------------------------------------------------- mega0:
// transposes (blocks 0..1151) | obs-LN (1152..3199) | role_count (3200..3327)
// | rnn passthrough copy (3328..3455). All independent.
DEVINL void tp_tile(const float* __restrict__ s, u16* __restrict__ d,
                    int R, int C, int bx, int by, int z)
{
  __shared__ u16 tile[32][33];
  const size_t mstride = (size_t)R * C;
  s += (size_t)z * mstride;
  d += (size_t)z * mstride;
  int r0 = bx * 32, c0 = by * 32;
  int tx = threadIdx.x & 31, ty = threadIdx.x >> 5;
#pragma unroll
  for (int i = 0; i < 32; i += 8)
    tile[ty + i][tx] = f2b(s[(size_t)(r0 + ty + i) * C + (c0 + tx)]);
  __syncthreads();
#pragma unroll
  for (int i = 0; i < 32; i += 8)
    d[(size_t)(c0 + ty + i) * R + (r0 + tx)] = tile[tx][ty + i];
}

__global__ __launch_bounds__(256) void mega0(
    const float* W0, const float* W1, const float* Wr0, const float* Wr1, const float* Wh0,
    u16* W0t, u16* W1t, u16* Wr0t, u16* Wr1t, u16* Wh0t,
    const float* __restrict__ obs, const float* __restrict__ fn_s,
    const float* __restrict__ fn_b, u16* __restrict__ obs_n,
    const int* __restrict__ rid, int* __restrict__ blkCnt,
    const float* __restrict__ rnn, float* __restrict__ outRnn)
{
  int b = blockIdx.x;
  const int tid = threadIdx.x;
  if (b < 1152) {
    if (b < 128)      {            tp_tile(W0, W0t, 256, 512, b % 8,  b / 8, 0); }
    else if (b < 384) { b -= 128;  tp_tile(W1, W1t, 512, 512, b % 16, b / 16, 0); }
    else if (b < 576) { b -= 384;  int t = b / 8;  tp_tile(Wr0, Wr0t, 256, 128, b % 8,  t % 4,  t / 4); }
    else if (b < 960) { b -= 576;  int t = b / 4;  tp_tile(Wr1, Wr1t, 128, 512, b % 4,  t % 16, t / 16); }
    else              { b -= 960;  int t = b / 16; tp_tile(Wh0, Wh0t, 512, 64,  b % 16, t % 2,  t / 2); }
  } else if (b < 3200) {
    b -= 1152;
    const int lane = tid & 63, wave = tid >> 6;
#pragma unroll
    for (int it = 0; it < 4; ++it) {
      int row = b * 16 + wave * 4 + it;
      const float* xr = obs + (size_t)row * 256 + lane * 4;
      float x[4] __attribute__((aligned(16)));
      *(float4*)x = *(const float4*)xr;
      float s = 0.f, s2 = 0.f;
#pragma unroll
      for (int p = 0; p < 4; ++p) { s += x[p]; s2 += x[p] * x[p]; }
#pragma unroll
      for (int o = 32; o > 0; o >>= 1) { s += __shfl_xor(s, o, 64); s2 += __shfl_xor(s2, o, 64); }
      float m = s * (1.f / 256.f);
      float v = s2 * (1.f / 256.f) - m * m;
      float inv = rsqrtf(v + 1e-5f);
      u16 yu[4] __attribute__((aligned(8)));
#pragma unroll
      for (int p = 0; p < 4; ++p)
        yu[p] = f2b((x[p] - m) * inv * fn_s[lane * 4 + p] + fn_b[lane * 4 + p]);
      *(uint2*)(obs_n + (size_t)row * 256 + lane * 4) = *(uint2*)yu;
    }
  } else if (b < 3328) {
    b -= 3200;
    __shared__ int h[NROLE];
    if (tid < NROLE) h[tid] = 0;
    __syncthreads();
    atomicAdd(&h[rid[b * 256 + tid]], 1);
    __syncthreads();
    if (tid < NROLE) blkCnt[b * NROLE + tid] = h[tid];
  } else {
    b -= 3328;
    const float4* src = (const float4*)rnn;
    float4* dst = (float4*)outRnn;
    int base = (b * 256 + tid) * 4;
#pragma unroll
    for (int i = 0; i < 4; ++i) dst[base + i] = src[base + i];
  }
}

// ---------------------------------------------------------------- fill2: scan (redundant per block) + fill
__global__ __launch_bounds__(256) void fill2(
    const int* __restrict__ rid, const int* __restrict__ blkCnt,
    int* __restrict__ bucket, int* __restrict__ baseArr, int* __restrict__ cntArr)
{
  __shared__ int c[128 * NROLE];
  __shared__ int preArr[NROLE], scnt[NROLE], sbase[NROLE], h[NROLE];
  const int tid = threadIdx.x;
  const int bx = blockIdx.x;
  for (int i = tid; i < 128 * NROLE; i += 256) c[i] = blkCnt[i];
  if (tid < NROLE) h[tid] = 0;
  __syncthreads();
  if (tid < NROLE) {
    int k = tid, run = 0, pre = 0;
    for (int b = 0; b < 128; ++b) { if (b == bx) pre = run; run += c[b * NROLE + k]; }
    scnt[k] = run; preArr[k] = pre;
  }
  __syncthreads();
  if (tid == 0) {
    int r = 0;
    for (int k = 0; k < NROLE; ++k) { sbase[k] = r; r += scnt[k]; }
  }
  __syncthreads();
  if (bx == 0 && tid < NROLE) { baseArr[tid] = sbase[tid]; cntArr[tid] = scnt[tid]; }
  int i = bx * 256 + tid;
  int k = rid[i];
  int pos = atomicAdd(&h[k], 1);
  bucket[sbase[k] + preArr[k] + pos] = i;
}

// ---------------------------------------------------------------- fused dense GEMM + ReLU + LN
// BM=64, BK=128 (A dbuf 2x16KB; half the barrier drains of BK=64).
// 4 waves x 128 cols, acc[4][8]; B reg-prefetched one 32-K chunk ahead from global.
// Staging/swizzle pattern identical to r10's route1_k (correctness-verified).
template <int K>
__global__ __launch_bounds__(256, 2) void gemm_ln(
    const u16* __restrict__ A, const u16* __restrict__ Bt,
    const float* __restrict__ bias, const float* __restrict__ lnsc,
    const float* __restrict__ lnbi, u16* __restrict__ C)
{
  constexpr int BK = 128, NI = K / BK, NC = K / 32;
  __shared__ __align__(16) u16 As[2][64 * BK];   // 2 x 16 KB
  __shared__ float redS[64][4];
  __shared__ float redSS[64][4];
  __shared__ float prm[1536];
  const int tid = threadIdx.x;
  const int rowBase = blockIdx.x * 64;
  const int lane = tid & 63, wave = tid >> 6;
#pragma unroll
  for (int i = tid; i < 512; i += 256) {
    prm[i] = bias[i]; prm[512 + i] = lnsc[i]; prm[1024 + i] = lnbi[i];
  }
  u32 aOff[4];
#pragma unroll
  for (int r = 0; r < 4; ++r) {
    int row = r * 16 + (tid >> 4);
    int chunk = tid & 15;
    aOff[r] = (u32)(rowBase + row) * (u32)K + (u32)((chunk ^ (row & 7)) * 8);
  }
  const int quad = lane >> 4, lm = lane & 15, l7 = lm & 7;
  const int wn = wave * 128;
  u32 bOff[8];
#pragma unroll
  for (int j = 0; j < 8; ++j)
    bOff[j] = (u32)(wn + j * 16 + lm) * (u32)K + (u32)(quad * 8);

  f32x4 acc[4][8] = {};

#pragma unroll
  for (int r = 0; r < 4; ++r)
    gll16(A + aOff[r], &As[0][r * 2048 + wave * 512]);
  bf16x8 bP[8];
#pragma unroll
  for (int j = 0; j < 8; ++j)
    bP[j] = *(const bf16x8*)(Bt + bOff[j]);
  __syncthreads();

  for (int i = 0; i < NI; ++i) {
    const u16* Ab = As[i & 1];
    if (i + 1 < NI) {
#pragma unroll
      for (int r = 0; r < 4; ++r)
        gll16(A + aOff[r] + (i + 1) * BK, &As[(i + 1) & 1][r * 2048 + wave * 512]);
    }
#pragma unroll
    for (int c = 0; c < 4; ++c) {
      const int g = i * 4 + c;
      bf16x8 bN[8];
      if (g + 1 < NC) {
#pragma unroll
        for (int j = 0; j < 8; ++j)
          bN[j] = *(const bf16x8*)(Bt + bOff[j] + (g + 1) * 32);
      }
      const int kc = c * 4;
      bf16x8 af[4];
#pragma unroll
      for (int i2 = 0; i2 < 4; ++i2)
        af[i2] = *(const bf16x8*)&Ab[(i2 * 16 + lm) * BK + (((quad + kc) ^ l7) * 8)];
#pragma unroll
      for (int i2 = 0; i2 < 4; ++i2)
#pragma unroll
        for (int j = 0; j < 8; ++j)
          acc[i2][j] = MFMA(af[i2], bP[j], acc[i2][j], 0, 0, 0);
      if (g + 1 < NC) {
#pragma unroll
        for (int j = 0; j < 8; ++j) bP[j] = bN[j];
      }
    }
    __syncthreads();
  }

#pragma unroll
  for (int i2 = 0; i2 < 4; ++i2) {
#pragma unroll
    for (int r2 = 0; r2 < 4; ++r2) {
      float s = 0.f, ss = 0.f;
#pragma unroll
      for (int j = 0; j < 8; ++j) {
        float v = fmaxf(acc[i2][j][r2] + prm[wn + j * 16 + lm], 0.f);
        acc[i2][j][r2] = v;
        s += v; ss += v * v;
      }
#pragma unroll
      for (int o = 1; o < 16; o <<= 1) { s += __shfl_xor(s, o, 64); ss += __shfl_xor(ss, o, 64); }
      if (lm == 0) {
        int rowL = i2 * 16 + quad * 4 + r2;
        redS[rowL][wave] = s;
        redSS[rowL][wave] = ss;
      }
    }
  }
  __syncthreads();
#pragma unroll
  for (int i2 = 0; i2 < 4; ++i2) {
#pragma unroll
    for (int r2 = 0; r2 < 4; ++r2) {
      int rowL = i2 * 16 + quad * 4 + r2;
      float ts  = redS[rowL][0] + redS[rowL][1] + redS[rowL][2] + redS[rowL][3];
      float tss = redSS[rowL][0] + redSS[rowL][1] + redSS[rowL][2] + redSS[rowL][3];
      float m = ts * (1.f / 512.f);
      float var = tss * (1.f / 512.f) - m * m;
      float inv = rsqrtf(var + 1e-5f);
      size_t base = (size_t)(rowBase + rowL) * 512;
#pragma unroll
      for (int j = 0; j < 8; ++j) {
        int col = wn + j * 16 + lm;
        float y = (acc[i2][j][r2] - m) * inv * prm[512 + col] + prm[1024 + col];
        C[base + col] = f2b(y);
      }
    }
  }
}

// ---------------------------------------------------------------- fused role route + head (r8-verbatim)
// LDS (u16 idx): e/ea [0,16384) | A0 [16384,24576)
//   aliases after stage0: r1 [16384,20480), h0s [20480,22656), h1s(f32) [22656,24960)
__global__ __launch_bounds__(256, 3) void route_head(
    const u16* __restrict__ obs_n, const u16* __restrict__ e,
    const u16* __restrict__ Wr0t, const float* __restrict__ br0,
    const u16* __restrict__ Wr1t, const float* __restrict__ br1,
    const u16* __restrict__ Wh0t, const float* __restrict__ bh0,
    const float* __restrict__ Wh1, const float* __restrict__ bh1,
    const float* __restrict__ Wh2, const float* __restrict__ bh2,
    const float* __restrict__ avail,
    const int* __restrict__ bucket, const int* __restrict__ baseArr,
    const int* __restrict__ cntArr, float* __restrict__ outLogits)
{
  __shared__ __align__(16) u16 sm[24960];
  __shared__ float prm[704];        // br0 128 | br1 512 | bh0 64
  const int tid = threadIdx.x;

  int role = 0, rem = blockIdx.x, cnt;
  for (;;) {
    cnt = cntArr[role];
    int tiles = (cnt + 31) >> 5;
    if (rem < tiles) break;
    rem -= tiles;
    if (++role >= NROLE) return;
  }
  const int limit = cnt;
  const int rowBase = rem * 32;
  const int roleBase = baseArr[role];

  const int lane = tid & 63, wave = tid >> 6;
  const int quad = lane >> 4, lm = lane & 15, l7 = lm & 7;

#pragma unroll
  for (int r = 0; r < 4; ++r) {
    int lrow = r * 8 + (tid >> 5);
    int i = rowBase + lrow;
    if (i >= limit) i = rowBase;
    int grow = bucket[roleBase + i];
    gll16(obs_n + (u32)grow * 256u + (u32)(((tid & 31) ^ (lrow & 7)) * 8),
          &sm[16384 + r * 2048 + wave * 512]);
  }
#pragma unroll
  for (int r = 0; r < 8; ++r) {
    int lrow = r * 4 + wave;
    int i = rowBase + lrow;
    if (i >= limit) i = rowBase;
    int grow = bucket[roleBase + i];
    int chunk = tid & 63;
    int sw = (chunk & 56) | ((chunk ^ lrow) & 7);
    gll16(e + (u32)grow * 512u + (u32)(sw * 8), &sm[r * 2048 + wave * 512]);
  }
  {
    if (tid < 128) prm[tid] = br0[role * 128 + tid];
    for (int i = tid; i < 512; i += 256) prm[128 + i] = br1[role * 512 + i];
    if (tid < 64) prm[640 + tid] = bh0[role * 64 + tid];
  }
  __syncthreads();

  // ---- stage0: r1 = relu(A0 @ Wr0k^T + br0)  (N=128; wave = 32 cols); B ring-2
  const int wn0 = wave * 32;
  const u16* B0 = Wr0t + (size_t)role * 128 * 256;
  f32x4 acc0[2][2] = {};
  bf16x8 b0R[2][2];
#pragma unroll
  for (int p = 0; p < 2; ++p)
#pragma unroll
    for (int j = 0; j < 2; ++j)
      b0R[p][j] = *(const bf16x8*)(B0 + (u32)(wn0 + j * 16 + lm) * 256u + (u32)(quad * 8 + p * 32));
#pragma unroll
  for (int it = 0; it < 8; ++it) {
    bf16x8 cur0 = b0R[it & 1][0], cur1 = b0R[it & 1][1];
    if (it + 2 < 8) {
#pragma unroll
      for (int j = 0; j < 2; ++j)
        b0R[it & 1][j] = *(const bf16x8*)(B0 + (u32)(wn0 + j * 16 + lm) * 256u + (u32)(quad * 8 + (it + 2) * 32));
    }
    const int kc = it * 4;
    bf16x8 af[2];
#pragma unroll
    for (int i2 = 0; i2 < 2; ++i2)
      af[i2] = *(const bf16x8*)&sm[16384 + (i2 * 16 + lm) * 256 + (((quad + kc) ^ l7) * 8)];
#pragma unroll
    for (int i2 = 0; i2 < 2; ++i2) {
      acc0[i2][0] = MFMA(af[i2], cur0, acc0[i2][0], 0, 0, 0);
      acc0[i2][1] = MFMA(af[i2], cur1, acc0[i2][1], 0, 0, 0);
    }
  }
  __syncthreads();
  u16* r1 = sm + 16384;
#pragma unroll
  for (int i2 = 0; i2 < 2; ++i2) {
#pragma unroll
    for (int r2 = 0; r2 < 4; ++r2) {
      int row = i2 * 16 + quad * 4 + r2;
#pragma unroll
      for (int j = 0; j < 2; ++j) {
        int col = wn0 + j * 16 + lm;
        float v = fmaxf(acc0[i2][j][r2] + prm[col], 0.f);
        r1[row * 128 + (((col >> 3) ^ (row & 7)) * 8) + (col & 7)] = f2b(v);
      }
    }
  }
  __syncthreads();

  // ---- stage1: ea = relu(r1 @ Wr1k^T + br1) + e  (in-place over e)
  const int wn1 = wave * 128;
  const u16* B1 = Wr1t + (size_t)role * 512 * 128;
  f32x4 acc1[2][8] = {};
  bf16x8 b1P[8];
#pragma unroll
  for (int j = 0; j < 8; ++j)
    b1P[j] = *(const bf16x8*)(B1 + (u32)(wn1 + j * 16 + lm) * 128u + (u32)(quad * 8));
#pragma unroll
  for (int kk = 0; kk < 128; kk += 32) {
    bf16x8 b1N[8];
    if (kk + 32 < 128) {
#pragma unroll
      for (int j = 0; j < 8; ++j)
        b1N[j] = *(const bf16x8*)(B1 + (u32)(wn1 + j * 16 + lm) * 128u + (u32)(quad * 8 + kk + 32));
    }
    const int kc = kk >> 3;
    bf16x8 af[2];
#pragma unroll
    for (int i2 = 0; i2 < 2; ++i2)
      af[i2] = *(const bf16x8*)&r1[(i2 * 16 + lm) * 128 + (((quad + kc) ^ l7) * 8)];
#pragma unroll
    for (int i2 = 0; i2 < 2; ++i2)
#pragma unroll
      for (int j = 0; j < 8; ++j)
        acc1[i2][j] = MFMA(af[i2], b1P[j], acc1[i2][j], 0, 0, 0);
    if (kk + 32 < 128) {
#pragma unroll
      for (int j = 0; j < 8; ++j) b1P[j] = b1N[j];
    }
  }
#pragma unroll
  for (int i2 = 0; i2 < 2; ++i2) {
#pragma unroll
    for (int r2 = 0; r2 < 4; ++r2) {
      int row = i2 * 16 + quad * 4 + r2;
#pragma unroll
      for (int j = 0; j < 8; ++j) {
        int col = wn1 + j * 16 + lm;
        int addr = row * 512 + (((col >> 3) ^ (row & 7)) * 8) + (col & 7);
        float v = fmaxf(acc1[i2][j][r2] + prm[128 + col], 0.f) + b2f(sm[addr]);
        sm[addr] = f2b(v);
      }
    }
  }
  __syncthreads();

  // ---- stage2: h0 = relu(ea @ Wh0k^T + bh0)  (N=64; wave = 16 cols); B ring-4
  const int wn2 = wave * 16;
  const u16* B2 = Wh0t + (size_t)role * 64 * 512;
  f32x4 acc2[2] = {};
  bf16x8 b2R[4];
#pragma unroll
  for (int p = 0; p < 4; ++p)
    b2R[p] = *(const bf16x8*)(B2 + (u32)(wn2 + lm) * 512u + (u32)(quad * 8 + p * 32));
#pragma unroll
  for (int it = 0; it < 16; ++it) {
    bf16x8 cur = b2R[it & 3];
    if (it + 4 < 16)
      b2R[it & 3] = *(const bf16x8*)(B2 + (u32)(wn2 + lm) * 512u + (u32)(quad * 8 + (it + 4) * 32));
    const int kc = it * 4;
    bf16x8 af[2];
#pragma unroll
    for (int i2 = 0; i2 < 2; ++i2)
      af[i2] = *(const bf16x8*)&sm[(i2 * 16 + lm) * 512 + (((quad + kc) ^ l7) * 8)];
#pragma unroll
    for (int i2 = 0; i2 < 2; ++i2)
      acc2[i2] = MFMA(af[i2], cur, acc2[i2], 0, 0, 0);
  }
  u16* h0s = sm + 20480;
#pragma unroll
  for (int i2 = 0; i2 < 2; ++i2) {
#pragma unroll
    for (int r2 = 0; r2 < 4; ++r2) {
      int row = i2 * 16 + quad * 4 + r2;
      int col = wn2 + lm;
      h0s[row * 68 + col] = f2b(fmaxf(acc2[i2][r2] + prm[640 + col], 0.f));
    }
  }
  __syncthreads();

  // ---- stage3: per-thread tail
  {
    float* h1s = (float*)&sm[22656];
    const int r = tid >> 3;
    const int n0 = (tid & 7) * 4;
    const bool valid = (rowBase + r) < limit;
    const float* W1k = Wh1 + (size_t)role * 64 * 32;
    const float* W2k = Wh2 + (size_t)role * 32 * 32;
    float4 a1 = *(const float4*)(bh1 + role * 32 + n0);
#pragma unroll 8
    for (int j = 0; j < 64; ++j) {
      float hj = b2f(h0s[r * 68 + j]);
      float4 wv = *(const float4*)(W1k + j * 32 + n0);
      a1.x += hj * wv.x; a1.y += hj * wv.y; a1.z += hj * wv.z; a1.w += hj * wv.w;
    }
    h1s[r * 36 + n0 + 0] = fmaxf(a1.x, 0.f);
    h1s[r * 36 + n0 + 1] = fmaxf(a1.y, 0.f);
    h1s[r * 36 + n0 + 2] = fmaxf(a1.z, 0.f);
    h1s[r * 36 + n0 + 3] = fmaxf(a1.w, 0.f);
    __syncthreads();
    float4 a2 = *(const float4*)(bh2 + role * 32 + n0);
#pragma unroll 8
    for (int n = 0; n < 32; ++n) {
      float hn = h1s[r * 36 + n];
      float4 wv = *(const float4*)(W2k + n * 32 + n0);
      a2.x += hn * wv.x; a2.y += hn * wv.y; a2.z += hn * wv.z; a2.w += hn * wv.w;
    }
    if (valid) {
      int g = bucket[roleBase + rowBase + r];
      float4 av = *(const float4*)(avail + (size_t)g * 32 + n0);
      float4 o;
      o.x = (av.x > 0.5f) ? a2.x : -1e10f;
      o.y = (av.y > 0.5f) ? a2.y : -1e10f;
      o.z = (av.z > 0.5f) ? a2.z : -1e10f;
      o.w = (av.w > 0.5f) ? a2.w : -1e10f;
      *(float4*)(outLogits + (size_t)g * 32 + n0) = o;
    }
  }
}

// ---------------------------------------------------------------- launcher
extern "C" void kernel_launch(void* const* d_in, const int* in_sizes, int n_in,
                              void* d_out, int out_size, void* d_ws, size_t ws_size,
                              hipStream_t stream)
{
  const float* rnn  = (const float*)d_in[0];
  const float* obs  = (const float*)d_in[1];
  const float* avail= (const float*)d_in[3];
  const int*   rid  = (const int*)d_in[4];
  const float* fn_s = (const float*)d_in[5];
  const float* fn_b = (const float*)d_in[6];
  const float* W0   = (const float*)d_in[7];
  const float* b0   = (const float*)d_in[8];
  const float* ln0s = (const float*)d_in[9];
  const float* ln0b = (const float*)d_in[10];
  const float* W1   = (const float*)d_in[11];
  const float* b1   = (const float*)d_in[12];
  const float* ln1s = (const float*)d_in[13];
  const float* ln1b = (const float*)d_in[14];
  const float* Wr0  = (const float*)d_in[15];
  const float* br0  = (const float*)d_in[16];
  const float* Wr1  = (const float*)d_in[17];
  const float* br1  = (const float*)d_in[18];
  const float* Wh0  = (const float*)d_in[19];
  const float* bh0  = (const float*)d_in[20];
  const float* Wh1  = (const float*)d_in[21];
  const float* bh1  = (const float*)d_in[22];
  const float* Wh2  = (const float*)d_in[23];
  const float* bh2  = (const float*)d_in[24];

  const int ROWS = 32768;

  char* w = (char*)d_ws;
  auto carve = [&](size_t bytes) { char* p = w; w += (bytes + 255) & ~(size_t)255; return p; };
  u16* obs_n  = (u16*)carve((size_t)ROWS * 256 * 2);
  u16* bufA   = (u16*)carve((size_t)ROWS * 512 * 2);   // e0
  u16* bufB   = (u16*)carve((size_t)ROWS * 512 * 2);   // e
  u16* W0t    = (u16*)carve((size_t)512 * 256 * 2);
  u16* W1t    = (u16*)carve((size_t)512 * 512 * 2);
  u16* Wr0t   = (u16*)carve((size_t)6 * 128 * 256 * 2);
  u16* Wr1t   = (u16*)carve((size_t)6 * 512 * 128 * 2);
  u16* Wh0t   = (u16*)carve((size_t)6 * 64 * 512 * 2);
  int* bucket = (int*)carve((size_t)ROWS * 4);
  int* blkCnt = (int*)carve((size_t)128 * NROLE * 4);
  int* baseArr= (int*)carve(256);
  int* cntArr = (int*)carve(256);

  float* outLogits = (float*)d_out + (size_t)1024 * 512;

  // mega0: weight transposes + obs-LN + role_count + rnn passthrough
  mega0<<<3456, 256, 0, stream>>>(W0, W1, Wr0, Wr1, Wh0, W0t, W1t, Wr0t, Wr1t, Wh0t,
                                  obs, fn_s, fn_b, obs_n, rid, blkCnt, rnn, (float*)d_out);

  // scan+fill in one dispatch
  fill2<<<128, 256, 0, stream>>>(rid, blkCnt, bucket, baseArr, cntArr);

  // base MLP, LN fused + pipelined (BK=128)
  gemm_ln<256><<<512, 256, 0, stream>>>(obs_n, W0t, b0, ln0s, ln0b, bufA);
  gemm_ln<512><<<512, 256, 0, stream>>>(bufA, W1t, b1, ln1s, ln1b, bufB);

  // fused role route + full head
  route_head<<<1029, 256, 0, stream>>>(obs_n, bufB, Wr0t, br0, Wr1t, br1, Wh0t, bh0,
                                       Wh1, bh1, Wh2, bh2, avail,
                                       bucket, baseArr, cntArr, outLogits);
}